// Round 1
// baseline (156.048 us; speedup 1.0000x reference)
//
#include <hip/hip_runtime.h>

#define HH 512
#define WW 1024
#define NC 19
#define HWP (HH * WW)
#define NB 4
#define IGNORE_IDX 255

// ws layout: float acc[NB][NC][2]  (num, den)
__global__ __launch_bounds__(256) void tc_main(
    const float* __restrict__ preds,
    const float* __restrict__ targets,
    const float* __restrict__ flow,
    const int* __restrict__ labels,
    float* __restrict__ acc)
{
    const int b   = blockIdx.y;
    const int tid = threadIdx.x;

    float accn[NC];
    float accd[NC];
#pragma unroll
    for (int c = 0; c < NC; ++c) { accn[c] = 0.f; accd[c] = 0.f; }

    const float* tb = targets + (size_t)b * NC * HWP;
    const float* pb = preds   + (size_t)b * NC * HWP;
    const float2* fb = (const float2*)(flow + (size_t)b * HWP * 2);
    const int*   lb = labels  + (size_t)b * HWP;

    const int per_block = HWP / gridDim.x;
    const int base = blockIdx.x * per_block;

    for (int k = tid; k < per_block; k += blockDim.x) {
        const int pix = base + k;
        const int y = pix >> 10;       // WW = 1024
        const int x = pix & (WW - 1);

        const float2 f = fb[pix];
        const float fx = (float)x + f.x;
        const float fy = (float)y + f.y;
        const int rx = (int)rintf(fx);   // round-half-even == jnp.round
        const int ry = (int)rintf(fy);
        const bool valid = (rx >= 0) && (rx < WW) && (ry >= 0) && (ry < HH);
        const int rxc = min(max(rx, 0), WW - 1);
        const int ryc = min(max(ry, 0), HH - 1);
        const int spix = ryc * WW + rxc;

        const bool keep = (lb[pix] != IGNORE_IDX);

        // ---- targets softmax over channels ----
        float te[NC];
        float tmax = -INFINITY;
#pragma unroll
        for (int c = 0; c < NC; ++c) {
            te[c] = tb[(size_t)c * HWP + pix];
            tmax = fmaxf(tmax, te[c]);
        }
        float tsum = 0.f;
#pragma unroll
        for (int c = 0; c < NC; ++c) {
            te[c] = __expf(te[c] - tmax);
            tsum += te[c];
        }
        const float tinv = keep ? (1.0f / tsum) : 0.0f;

        // ---- preds softmax at warped (gathered) location ----
        float pe[NC];
        float pmax = -INFINITY;
#pragma unroll
        for (int c = 0; c < NC; ++c) {
            pe[c] = pb[(size_t)c * HWP + spix];
            pmax = fmaxf(pmax, pe[c]);
        }
        float psum = 0.f;
#pragma unroll
        for (int c = 0; c < NC; ++c) {
            pe[c] = __expf(pe[c] - pmax);
            psum += pe[c];
        }
        const float pinv = valid ? (1.0f / psum) : 0.0f;

        // ---- fuzzy IoU accumulation (all terms nonnegative) ----
#pragma unroll
        for (int c = 0; c < NC; ++c) {
            const float t = te[c] * tinv;
            const float p = pe[c] * pinv;
            const float pt = p * t;
            accn[c] += pt;
            accd[c] += p + t - pt;
        }
    }

    // ---- block reduction: wave shuffle, then LDS, then one atomic per value ----
#pragma unroll
    for (int c = 0; c < NC; ++c) {
        for (int off = 32; off > 0; off >>= 1) {
            accn[c] += __shfl_xor(accn[c], off);
            accd[c] += __shfl_xor(accd[c], off);
        }
    }

    __shared__ float s[4][NC][2];
    const int wave = tid >> 6;
    const int lane = tid & 63;
    if (lane == 0) {
#pragma unroll
        for (int c = 0; c < NC; ++c) {
            s[wave][c][0] = accn[c];
            s[wave][c][1] = accd[c];
        }
    }
    __syncthreads();
    if (tid < NC * 2) {
        const int c = tid >> 1;
        const int which = tid & 1;
        const float v = s[0][c][which] + s[1][c][which] + s[2][c][which] + s[3][c][which];
        atomicAdd(&acc[((size_t)b * NC + c) * 2 + which], v);
    }
}

__global__ void tc_final(const float* __restrict__ acc, float* __restrict__ out)
{
    if (threadIdx.x == 0 && blockIdx.x == 0) {
        float total = 0.f;
        for (int b = 0; b < NB; ++b) {
            float m = 0.f;
            for (int c = 0; c < NC; ++c) {
                const float n = acc[((size_t)b * NC + c) * 2 + 0];
                const float d = acc[((size_t)b * NC + c) * 2 + 1];
                m += n / d;
            }
            total += 1.0f - m / (float)NC;
        }
        out[0] = total / (float)NB;
    }
}

extern "C" void kernel_launch(void* const* d_in, const int* in_sizes, int n_in,
                              void* d_out, int out_size, void* d_ws, size_t ws_size,
                              hipStream_t stream) {
    const float* preds   = (const float*)d_in[0];
    const float* targets = (const float*)d_in[1];
    const float* flow    = (const float*)d_in[2];
    const int*   labels  = (const int*)d_in[3];
    float* acc = (float*)d_ws;

    hipMemsetAsync(acc, 0, (size_t)NB * NC * 2 * sizeof(float), stream);

    dim3 grid(256, NB);
    tc_main<<<grid, 256, 0, stream>>>(preds, targets, flow, labels, acc);
    tc_final<<<1, 64, 0, stream>>>(acc, (float*)d_out);
}